// Round 12
// baseline (1356.593 us; speedup 1.0000x reference)
//
#include <hip/hip_runtime.h>

// out = X · M,  M = (W^T W)/32 (symmetric 1024x1024)
// X: 65536x1024 fp32.  W: 1024x1024 fp32.  out: 65536x1024 fp32.
// Path A (ws >= 131 MB):
//   K1 prep: M-blocks FIRST (bid 0..255, R3's measured-best order), then
//     2048 convert blocks with CONTIGUOUS per-block 128KB streams (R3/R11's
//     8MB-strided thread pattern is the suspected 59%-BW cause; m13's
//     6.3 TB/s µbench is contiguous).
//   K2 gemm_2b: 256x256 tile, BK=32, 8 waves (2Mx4N, wave tile 128x64 =
//     32 MFMA/barrier — same as all best configs), ONE barrier/K-tile,
//     80 KB LDS (A 2-slot + B 3-slot rings) -> 2 BLOCKS/CU. The untried
//     cell: full-size wave tile + 2-block TLP (R6's 2-block regression used
//     64x64 wave tiles; R4/R7/R10/R11's 26%-MfmaUtil plateau all 1 block).
//     Ledger: iter j issues [A(j+1)x2, B(j+2)x2]; end-of-iter VMC(2) forces
//     A(j+1)+B(j+1) BEFORE closing BAR (cross-wave-safe); j=30 VMC(0).
//     Prologue [A0,B0,B1]+VMC(2) = steady-state invariant [B(j+1) in flight].
//     WAR: A slot (j+1)&1 freed at iter j-1's barrier; B slot (j+2)%3 freed
//     at iter j-1's barrier.
// Path B (small ws): R1's proven fused kernel.

typedef unsigned short u16;
typedef unsigned int u32;
typedef __bf16 bf16x8 __attribute__((ext_vector_type(8)));
typedef float f32x4 __attribute__((ext_vector_type(4)));

#define BAR() __builtin_amdgcn_s_barrier()
#define VMC(n) asm volatile("s_waitcnt vmcnt(" #n ")" ::: "memory")
#define SCHED0() __builtin_amdgcn_sched_barrier(0)

__device__ __forceinline__ u16 f2bf(float f) {  // RNE fp32->bf16
  u32 u = __float_as_uint(f);
  u += 0x7fffu + ((u >> 16) & 1u);
  return (u16)(u >> 16);
}

__device__ __forceinline__ void gload_lds16(const void* g, void* l) {
  __builtin_amdgcn_global_load_lds((const __attribute__((address_space(1))) u32*)g,
                                   (__attribute__((address_space(3))) u32*)l,
                                   16, 0, 0);
}

// ---------------- K1: prep = {M-tiles first ; contiguous X->bf16 convert} -----
__global__ __launch_bounds__(256) void prep(const float* __restrict__ X,
                                            const float* __restrict__ W,
                                            u16* __restrict__ Xb,
                                            u16* __restrict__ Mb) {
  __shared__ float w1[32][64];
  __shared__ float w2[32][64];
  const int bid = blockIdx.x;
  const int t = threadIdx.x;
  if (bid >= 256) {
    // ---- convert: block owns a CONTIGUOUS 32768-float (128KB) range ----
    const int cid = bid - 256;  // 0..2047
    const float* src = X + (size_t)cid * 32768;
    u16* dst = Xb + (size_t)cid * 32768;
#pragma unroll 4
    for (int it = 0; it < 32; ++it) {
      const int o = it * 1024 + t * 4;
      const float4 v = *(const float4*)(src + o);
      ushort4 d;
      d.x = f2bf(v.x); d.y = f2bf(v.y); d.z = f2bf(v.z); d.w = f2bf(v.w);
      *(ushort4*)(dst + o) = d;
    }
    return;
  }
  // ---- M = (W^T W)/32, 64x64 tile per block (dispatched first) ----
  const int mb = bid;  // 0..255
  const int i0 = (mb >> 4) * 64;
  const int j0 = (mb & 15) * 64;
  const int tx = t & 15, ty = t >> 4;
  float acc[4][4] = {};
  for (int u0 = 0; u0 < 1024; u0 += 32) {
    __syncthreads();
#pragma unroll
    for (int p = 0; p < 2; ++p) {
      int idx = p * 256 + t;
      int lu = idx >> 4, lc = (idx & 15) * 4;
      *(float4*)&w1[lu][lc] = *(const float4*)(W + (size_t)(u0 + lu) * 1024 + i0 + lc);
      *(float4*)&w2[lu][lc] = *(const float4*)(W + (size_t)(u0 + lu) * 1024 + j0 + lc);
    }
    __syncthreads();
#pragma unroll 8
    for (int u = 0; u < 32; ++u) {
      float4 a = *(const float4*)&w1[u][ty * 4];
      float4 b = *(const float4*)&w2[u][tx * 4];
      float av[4] = {a.x, a.y, a.z, a.w};
      float bv[4] = {b.x, b.y, b.z, b.w};
#pragma unroll
      for (int e = 0; e < 4; ++e)
#pragma unroll
        for (int f = 0; f < 4; ++f)
          acc[e][f] += av[e] * bv[f];
    }
  }
  const float s = 0.03125f;
#pragma unroll
  for (int e = 0; e < 4; ++e) {
    ushort4 v;
    v.x = f2bf(acc[e][0] * s);
    v.y = f2bf(acc[e][1] * s);
    v.z = f2bf(acc[e][2] * s);
    v.w = f2bf(acc[e][3] * s);
    *(ushort4*)(Mb + (size_t)(i0 + ty * 4 + e) * 1024 + j0 + tx * 4) = v;
  }
}

// ---------------- K2: 2-blocks/CU, 1-barrier, full wave tile ------------------
__global__ __launch_bounds__(512, 4) void gemm_2b(const u16* __restrict__ Xb,
                                                  const u16* __restrict__ Mb,
                                                  float* __restrict__ out) {
  __shared__ u16 lA[2][8192];  // 2 slots x 256 rows x 32 bf16 = 32 KB
  __shared__ u16 lB[3][8192];  // 3 slots = 48 KB  (total 80 KB -> 2 blocks/CU)

  const int p = blockIdx.x;                  // nwg = 1024 (%8==0)
  const int wg = (p & 7) * 128 + (p >> 3);   // chunked XCD swizzle
  const int bm = wg >> 2;                    // 0..255
  const int bn = wg & 3;                     // 0..3 (A-panel shared by 4 on XCD)
  const size_t r0 = (size_t)bm * 256;
  const int c0 = bn * 256;

  const int t = threadIdx.x;
  const int lane = t & 63;
  const int w = t >> 6;
  const int wr = w >> 2, wc = w & 3;         // 2x4 wave grid, wave tile 128x64
  const int fr = lane & 15;
  const int kc = lane >> 4;

  const int srow = t >> 2;                   // 0..127
  const int scl = t & 3;
  const int csw = scl ^ ((srow >> 1) & 3);   // XOR chunk swizzle (involution)
  const u16* gA  = Xb + (r0 + srow) * 1024 + csw * 8;          // pre-swz src
  const u16* gA2 = Xb + (r0 + 128 + srow) * 1024 + csw * 8;
  const u16* gB  = Mb + (size_t)(c0 + srow) * 1024 + csw * 8;
  const u16* gB2 = Mb + (size_t)(c0 + 128 + srow) * 1024 + csw * 8;
  u16* aDst = &lA[0][w * 512];               // wave-uniform linear dest
  u16* bDst = &lB[0][w * 512];

  f32x4 acc[8][4] = {};

  // ---- prologue: A0 -> slotA0, B0 -> slotB0, B1 -> slotB1; VMC(2)+BAR ----
  gload_lds16(gA, aDst);             gload_lds16(gA2, aDst + 4096);
  gload_lds16(gB, bDst);             gload_lds16(gB2, bDst + 4096);
  gload_lds16(gB + 32, bDst + 8192); gload_lds16(gB2 + 32, bDst + 8192 + 4096);
  VMC(2);   // forces A0,B0; leaves B1 (= steady-state in-flight invariant)
  SCHED0();
  BAR();

  int rbB = 0, wbB = 2;  // j%3 and (j+2)%3 running counters
  for (int j = 0; j < 32; ++j) {
    const u16* bA = &lA[j & 1][0];
    const u16* bB = &lB[rbB][0];

    // stage: A(j+1) first (forced at THIS iter's end), then B(j+2)
    if (j <= 30) {
      const int ka = (j + 1) * 32;
      gload_lds16(gA + ka, aDst + ((j + 1) & 1) * 8192);
      gload_lds16(gA2 + ka, aDst + ((j + 1) & 1) * 8192 + 4096);
    }
    if (j <= 29) {
      const int kb = (j + 2) * 32;
      gload_lds16(gB + kb, bDst + wbB * 8192);
      gload_lds16(gB2 + kb, bDst + wbB * 8192 + 4096);
    }
    // fragment reads (compiler emits counted lgkmcnt before each MFMA)
    bf16x8 bf[4], af[8];
#pragma unroll
    for (int n = 0; n < 4; ++n) {
      const int row = wc * 64 + n * 16 + fr;
      const int cs = kc ^ ((row >> 1) & 3);
      bf[n] = *(const bf16x8*)&bB[row * 32 + cs * 8];
    }
#pragma unroll
    for (int m = 0; m < 8; ++m) {
      const int row = wr * 128 + m * 16 + fr;
      const int cs = kc ^ ((row >> 1) & 3);
      af[m] = *(const bf16x8*)&bA[row * 32 + cs * 8];
    }
    __builtin_amdgcn_s_setprio(1);
#pragma unroll
    for (int m = 0; m < 8; ++m)
#pragma unroll
      for (int n = 0; n < 4; ++n)
        acc[m][n] = __builtin_amdgcn_mfma_f32_16x16x32_bf16(af[m], bf[n],
                                                            acc[m][n], 0, 0, 0);
    __builtin_amdgcn_s_setprio(0);
    // cross-wave publish BEFORE the closing barrier:
    //   outstanding = [B(j+1)2, A(j+1)2, B(j+2)2] -> VMC(2) forces B(j+1),A(j+1)
    if (j <= 29) {
      VMC(2);
    } else if (j == 30) {
      VMC(0);   // forces A31, B31
    }
    SCHED0();
    BAR();
    rbB = (rbB == 2) ? 0 : rbB + 1;
    wbB = (wbB == 2) ? 0 : wbB + 1;
  }

  // ---- epilogue: C layout col=lane&15, row=(lane>>4)*4+reg ----
  const int ocol = lane & 15;
  const int orow = (lane >> 4) * 4;
#pragma unroll
  for (int m = 0; m < 8; ++m) {
    const size_t rbase = (r0 + wr * 128 + m * 16 + orow) * 1024;
#pragma unroll
    for (int n = 0; n < 4; ++n) {
      float* o = out + rbase + (c0 + wc * 64 + n * 16 + ocol);
      o[0] = acc[m][n][0];
      o[1024] = acc[m][n][1];
      o[2048] = acc[m][n][2];
      o[3072] = acc[m][n][3];
    }
  }
}

// ---------------- fallback (R1's proven fused kernel, 2 MB ws) ----------------
__global__ __launch_bounds__(256) void gemm_fused(const float* __restrict__ X,
                                                  const u16* __restrict__ Mb,
                                                  float* __restrict__ out) {
  __shared__ u16 lA[128 * 32];
  __shared__ u16 lB[128 * 32];
  const int p = blockIdx.x;
  const int wg = (p & 7) * 512 + (p >> 3);
  const int bm = wg >> 3;
  const int bn = wg & 7;
  const size_t r0 = (size_t)bm * 128;
  const int c0 = bn * 128;
  const int t = threadIdx.x;
  const int lane = t & 63;
  const int w = t >> 6;
  const int wr = w >> 1, wc = w & 1;
  const int ar_base = t >> 3;
  const int ac = t & 7;
  const int a_chunk = ac >> 1;
  const int a_half = ac & 1;
  const int fr = lane & 15;
  const int kc = lane >> 4;
  f32x4 acc[4][4] = {};
  for (int k0 = 0; k0 < 1024; k0 += 32) {
#pragma unroll
    for (int i = 0; i < 2; ++i) {
      const int slot0 = w * 128 + i * 64;
      const int slot = slot0 + lane;
      const int nr = slot >> 2;
      const int cc = (slot & 3) ^ ((nr >> 1) & 3);
      const char* g = (const char*)(Mb + (size_t)(c0 + nr) * 1024 + k0) + cc * 16;
      gload_lds16(g, (void*)(lB + slot0 * 8));
    }
#pragma unroll
    for (int q = 0; q < 4; ++q) {
      const int ar = q * 32 + ar_base;
      const float4 v = *(const float4*)(X + (r0 + ar) * 1024 + k0 + ac * 4);
      uint2 d;
      d.x = (u32)f2bf(v.x) | ((u32)f2bf(v.y) << 16);
      d.y = (u32)f2bf(v.z) | ((u32)f2bf(v.w) << 16);
      const int cs = a_chunk ^ ((ar >> 1) & 3);
      *(uint2*)&lA[ar * 32 + cs * 8 + a_half * 4] = d;
    }
    __syncthreads();
    bf16x8 afr[4], bfr[4];
#pragma unroll
    for (int m = 0; m < 4; ++m) {
      const int row = wr * 64 + m * 16 + fr;
      const int cs = kc ^ ((row >> 1) & 3);
      afr[m] = *(const bf16x8*)&lA[row * 32 + cs * 8];
    }
#pragma unroll
    for (int n = 0; n < 4; ++n) {
      const int row = wc * 64 + n * 16 + fr;
      const int cs = kc ^ ((row >> 1) & 3);
      bfr[n] = *(const bf16x8*)&lB[row * 32 + cs * 8];
    }
#pragma unroll
    for (int m = 0; m < 4; ++m)
#pragma unroll
      for (int n = 0; n < 4; ++n)
        acc[m][n] = __builtin_amdgcn_mfma_f32_16x16x32_bf16(afr[m], bfr[n],
                                                            acc[m][n], 0, 0, 0);
    __syncthreads();
  }
  const int ocol = lane & 15;
  const int orow = (lane >> 4) * 4;
#pragma unroll
  for (int m = 0; m < 4; ++m) {
    const size_t rbase = (r0 + wr * 64 + m * 16 + orow) * 1024;
#pragma unroll
    for (int n = 0; n < 4; ++n) {
      float* o = out + rbase + (c0 + wc * 64 + n * 16 + ocol);
      o[0] = acc[m][n][0];
      o[1024] = acc[m][n][1];
      o[2048] = acc[m][n][2];
      o[3072] = acc[m][n][3];
    }
  }
}

__global__ __launch_bounds__(256) void compute_M_fb(const float* __restrict__ W,
                                                    u16* __restrict__ Mb) {
  __shared__ float w1[32][64];
  __shared__ float w2[32][64];
  const int t = threadIdx.x;
  const int i0 = blockIdx.y * 64;
  const int j0 = blockIdx.x * 64;
  const int tx = t & 15, ty = t >> 4;
  float acc[4][4] = {};
  for (int u0 = 0; u0 < 1024; u0 += 32) {
    __syncthreads();
#pragma unroll
    for (int p = 0; p < 2; ++p) {
      int idx = p * 256 + t;
      int lu = idx >> 4, lc = (idx & 15) * 4;
      *(float4*)&w1[lu][lc] = *(const float4*)(W + (size_t)(u0 + lu) * 1024 + i0 + lc);
      *(float4*)&w2[lu][lc] = *(const float4*)(W + (size_t)(u0 + lu) * 1024 + j0 + lc);
    }
    __syncthreads();
#pragma unroll 8
    for (int u = 0; u < 32; ++u) {
      float4 a = *(const float4*)&w1[u][ty * 4];
      float4 b = *(const float4*)&w2[u][tx * 4];
      float av[4] = {a.x, a.y, a.z, a.w};
      float bv[4] = {b.x, b.y, b.z, b.w};
#pragma unroll
      for (int e = 0; e < 4; ++e)
#pragma unroll
        for (int f = 0; f < 4; ++f)
          acc[e][f] += av[e] * bv[f];
    }
  }
  const float s = 0.03125f;
#pragma unroll
  for (int e = 0; e < 4; ++e) {
    ushort4 v;
    v.x = f2bf(acc[e][0] * s);
    v.y = f2bf(acc[e][1] * s);
    v.z = f2bf(acc[e][2] * s);
    v.w = f2bf(acc[e][3] * s);
    *(ushort4*)(Mb + (size_t)(i0 + ty * 4 + e) * 1024 + j0 + tx * 4) = v;
  }
}

extern "C" void kernel_launch(void* const* d_in, const int* in_sizes, int n_in,
                              void* d_out, int out_size, void* d_ws, size_t ws_size,
                              hipStream_t stream) {
  const float* X = (const float*)d_in[0];
  const float* W = (const float*)d_in[1];
  float* out = (float*)d_out;
  u16* Mb = (u16*)d_ws;                                 // 2 MB
  u16* Xb = (u16*)((char*)d_ws + (size_t)(1 << 21));    // 128 MB

  const size_t need = (size_t)(1 << 21) + (size_t)64 * 1024 * 1024 * 2;
  if (ws_size >= need) {
    prep<<<2304, 256, 0, stream>>>(X, W, Xb, Mb);
    gemm_2b<<<1024, 512, 0, stream>>>(Xb, Mb, out);
  } else {
    compute_M_fb<<<dim3(16, 16), 256, 0, stream>>>(W, Mb);
    gemm_fused<<<4096, 256, 0, stream>>>(X, Mb, out);
  }
}

// Round 13
// 393.794 us; speedup vs baseline: 3.4449x; 3.4449x over previous
//
#include <hip/hip_runtime.h>

// out = X · M,  M = (W^T W)/32 (symmetric 1024x1024)
// X: 65536x1024 fp32.  W: 1024x1024 fp32.  out: 65536x1024 fp32.
// Path A (ws >= 131 MB):
//   K1 prep: M-blocks FIRST, then contiguous X->bf16 convert (~80us, R12).
//   K2 gemm_ad: 256x256 tile, BK=32, 8 waves (2Mx4N, wave tile 128x64).
//     A: DIRECT-TO-REGISTER fragments (global_load_dwordx4, 16 rows x 64B
//        coalesced), register double-buffer afA/afB, lookahead 1 — A latency
//        decoupled from barriers (R12 proved 2-blocks/CU impossible at this
//        wave tile: acc[8][4]=128 VGPRs; so cross-iter overlap must come from
//        registers, not TLP).
//     B: global_load_lds 4-slot LDS ring (R11-proven layout), lookahead 2.
//     Ledger: iter j issues [B(j+2)x2, A(j+1)x8]; VMC(10) before MFMA forces
//     A(j) + B(j+1); BAR after MFMA publishes B(j+1) (VMC-before-BAR rule).
//     Tail: j=30 VMC(8), j=31 VMC(0). Prologue [A0,B0,B1] + VMC(2) + BAR.
// Path B (small ws): R1's proven fused kernel.

typedef unsigned short u16;
typedef unsigned int u32;
typedef __bf16 bf16x8 __attribute__((ext_vector_type(8)));
typedef float f32x4 __attribute__((ext_vector_type(4)));

#define BAR() __builtin_amdgcn_s_barrier()
#define VMC(n) asm volatile("s_waitcnt vmcnt(" #n ")" ::: "memory")
#define SCHED0() __builtin_amdgcn_sched_barrier(0)

__device__ __forceinline__ u16 f2bf(float f) {  // RNE fp32->bf16
  u32 u = __float_as_uint(f);
  u += 0x7fffu + ((u >> 16) & 1u);
  return (u16)(u >> 16);
}

__device__ __forceinline__ void gload_lds16(const void* g, void* l) {
  __builtin_amdgcn_global_load_lds((const __attribute__((address_space(1))) u32*)g,
                                   (__attribute__((address_space(3))) u32*)l,
                                   16, 0, 0);
}

__device__ __forceinline__ void load16(const void* p, bf16x8& d) {
  asm volatile("global_load_dwordx4 %0, %1, off"
               : "=&v"(d) : "v"(p) : "memory");
}

// ---------------- K1: prep = {M-tiles first ; contiguous X->bf16 convert} -----
__global__ __launch_bounds__(256) void prep(const float* __restrict__ X,
                                            const float* __restrict__ W,
                                            u16* __restrict__ Xb,
                                            u16* __restrict__ Mb) {
  __shared__ float w1[32][64];
  __shared__ float w2[32][64];
  const int bid = blockIdx.x;
  const int t = threadIdx.x;
  if (bid >= 256) {
    const int cid = bid - 256;  // 0..2047, contiguous 128KB stream each
    const float* src = X + (size_t)cid * 32768;
    u16* dst = Xb + (size_t)cid * 32768;
#pragma unroll 4
    for (int it = 0; it < 32; ++it) {
      const int o = it * 1024 + t * 4;
      const float4 v = *(const float4*)(src + o);
      ushort4 d;
      d.x = f2bf(v.x); d.y = f2bf(v.y); d.z = f2bf(v.z); d.w = f2bf(v.w);
      *(ushort4*)(dst + o) = d;
    }
    return;
  }
  const int mb = bid;  // 0..255, dispatched first
  const int i0 = (mb >> 4) * 64;
  const int j0 = (mb & 15) * 64;
  const int tx = t & 15, ty = t >> 4;
  float acc[4][4] = {};
  for (int u0 = 0; u0 < 1024; u0 += 32) {
    __syncthreads();
#pragma unroll
    for (int p = 0; p < 2; ++p) {
      int idx = p * 256 + t;
      int lu = idx >> 4, lc = (idx & 15) * 4;
      *(float4*)&w1[lu][lc] = *(const float4*)(W + (size_t)(u0 + lu) * 1024 + i0 + lc);
      *(float4*)&w2[lu][lc] = *(const float4*)(W + (size_t)(u0 + lu) * 1024 + j0 + lc);
    }
    __syncthreads();
#pragma unroll 8
    for (int u = 0; u < 32; ++u) {
      float4 a = *(const float4*)&w1[u][ty * 4];
      float4 b = *(const float4*)&w2[u][tx * 4];
      float av[4] = {a.x, a.y, a.z, a.w};
      float bv[4] = {b.x, b.y, b.z, b.w};
#pragma unroll
      for (int e = 0; e < 4; ++e)
#pragma unroll
        for (int f = 0; f < 4; ++f)
          acc[e][f] += av[e] * bv[f];
    }
  }
  const float s = 0.03125f;
#pragma unroll
  for (int e = 0; e < 4; ++e) {
    ushort4 v;
    v.x = f2bf(acc[e][0] * s);
    v.y = f2bf(acc[e][1] * s);
    v.z = f2bf(acc[e][2] * s);
    v.w = f2bf(acc[e][3] * s);
    *(ushort4*)(Mb + (size_t)(i0 + ty * 4 + e) * 1024 + j0 + tx * 4) = v;
  }
}

// ---------------- K2: A-direct-to-register GEMM -------------------------------
__global__ __launch_bounds__(512, 2) void gemm_ad(const u16* __restrict__ Xb,
                                                  const u16* __restrict__ Mb,
                                                  float* __restrict__ out) {
  __shared__ u16 lB[4][8192];  // 4 slots x 256 rows x 32 bf16 = 64 KB (B only)

  const int p = blockIdx.x;                  // nwg = 1024 (%8==0)
  const int wg = (p & 7) * 128 + (p >> 3);   // chunked XCD swizzle
  const int bm = wg >> 2;                    // 0..255
  const int bn = wg & 3;                     // 0..3 (A-panel shared by 4 on XCD)
  const size_t r0 = (size_t)bm * 256;
  const int c0 = bn * 256;

  const int t = threadIdx.x;
  const int lane = t & 63;
  const int w = t >> 6;
  const int wr = w >> 2, wc = w & 3;         // 2x4 wave grid, wave tile 128x64
  const int fr = lane & 15;
  const int kc = lane >> 4;

  // B staging (R11-proven: pre-swizzled src, linear wave-uniform dest)
  const int srow = t >> 2;
  const int scl = t & 3;
  const int csw = scl ^ ((srow >> 1) & 3);
  const u16* gB  = Mb + (size_t)(c0 + srow) * 1024 + csw * 8;
  const u16* gB2 = Mb + (size_t)(c0 + 128 + srow) * 1024 + csw * 8;
  u16* bDst = &lB[0][w * 512];

  // A-direct per-lane base: row (r0 + wr*128 + fr), k-chunk kc; +m*16 rows
  // via m*16384 elems; +K-tile via j*32 elems. 16 rows x 64B per instruction.
  const u16* aP0 = Xb + (r0 + wr * 128 + fr) * 1024 + kc * 8;

  f32x4 acc[8][4] = {};
  bf16x8 afA[8], afB[8];

  // ---- prologue: A0 -> afA (8 loads), B0 -> slot0, B1 -> slot1 ----
#pragma unroll
  for (int m = 0; m < 8; ++m) load16(aP0 + m * 16384, afA[m]);
  gload_lds16(gB, bDst);             gload_lds16(gB2, bDst + 4096);
  gload_lds16(gB + 32, bDst + 8192); gload_lds16(gB2 + 32, bDst + 8192 + 4096);
  VMC(2);   // queue [A0 8, B0 2, B1 2] -> forces A0,B0; leaves B1
  SCHED0();
  BAR();    // publish B0

#define GITER(J, AFC, AFN)                                                     \
  {                                                                            \
    const int j_ = (J);                                                        \
    const int sb_ = (j_ + 2) & 3;                                              \
    if (j_ <= 29) {                                                            \
      gload_lds16(gB + (j_ + 2) * 32, bDst + sb_ * 8192);                      \
      gload_lds16(gB2 + (j_ + 2) * 32, bDst + sb_ * 8192 + 4096);              \
    }                                                                          \
    if (j_ <= 30) {                                                            \
      _Pragma("unroll")                                                        \
      for (int m = 0; m < 8; ++m)                                              \
        load16(aP0 + m * 16384 + (j_ + 1) * 32, AFN[m]);                       \
    }                                                                          \
    bf16x8 bf[4];                                                              \
    const u16* bB_ = &lB[j_ & 3][0];                                           \
    _Pragma("unroll")                                                          \
    for (int n = 0; n < 4; ++n) {                                              \
      const int row_ = wc * 64 + n * 16 + fr;                                  \
      const int cs_ = kc ^ ((row_ >> 1) & 3);                                  \
      bf[n] = *(const bf16x8*)&bB_[row_ * 32 + cs_ * 8];                       \
    }                                                                          \
    if (j_ <= 29) { VMC(10); } else if (j_ == 30) { VMC(8); } else { VMC(0); } \
    SCHED0();                                                                  \
    __builtin_amdgcn_s_setprio(1);                                             \
    _Pragma("unroll")                                                          \
    for (int m = 0; m < 8; ++m)                                                \
      _Pragma("unroll")                                                        \
      for (int n = 0; n < 4; ++n)                                              \
        acc[m][n] = __builtin_amdgcn_mfma_f32_16x16x32_bf16(AFC[m], bf[n],     \
                                                            acc[m][n], 0, 0, 0); \
    __builtin_amdgcn_s_setprio(0);                                             \
    BAR();                                                                     \
  }

  for (int jj = 0; jj < 16; ++jj) {
    GITER(2 * jj, afA, afB);
    GITER(2 * jj + 1, afB, afA);
  }
#undef GITER

  // ---- epilogue: C layout col=lane&15, row=(lane>>4)*4+reg ----
  const int ocol = lane & 15;
  const int orow = (lane >> 4) * 4;
#pragma unroll
  for (int m = 0; m < 8; ++m) {
    const size_t rbase = (r0 + wr * 128 + m * 16 + orow) * 1024;
#pragma unroll
    for (int n = 0; n < 4; ++n) {
      float* o = out + rbase + (c0 + wc * 64 + n * 16 + ocol);
      o[0] = acc[m][n][0];
      o[1024] = acc[m][n][1];
      o[2048] = acc[m][n][2];
      o[3072] = acc[m][n][3];
    }
  }
}

// ---------------- fallback (R1's proven fused kernel, 2 MB ws) ----------------
__global__ __launch_bounds__(256) void gemm_fused(const float* __restrict__ X,
                                                  const u16* __restrict__ Mb,
                                                  float* __restrict__ out) {
  __shared__ u16 lA[128 * 32];
  __shared__ u16 lB[128 * 32];
  const int p = blockIdx.x;
  const int wg = (p & 7) * 512 + (p >> 3);
  const int bm = wg >> 3;
  const int bn = wg & 7;
  const size_t r0 = (size_t)bm * 128;
  const int c0 = bn * 128;
  const int t = threadIdx.x;
  const int lane = t & 63;
  const int w = t >> 6;
  const int wr = w >> 1, wc = w & 1;
  const int ar_base = t >> 3;
  const int ac = t & 7;
  const int a_chunk = ac >> 1;
  const int a_half = ac & 1;
  const int fr = lane & 15;
  const int kc = lane >> 4;
  f32x4 acc[4][4] = {};
  for (int k0 = 0; k0 < 1024; k0 += 32) {
#pragma unroll
    for (int i = 0; i < 2; ++i) {
      const int slot0 = w * 128 + i * 64;
      const int slot = slot0 + lane;
      const int nr = slot >> 2;
      const int cc = (slot & 3) ^ ((nr >> 1) & 3);
      const char* g = (const char*)(Mb + (size_t)(c0 + nr) * 1024 + k0) + cc * 16;
      gload_lds16(g, (void*)(lB + slot0 * 8));
    }
#pragma unroll
    for (int q = 0; q < 4; ++q) {
      const int ar = q * 32 + ar_base;
      const float4 v = *(const float4*)(X + (r0 + ar) * 1024 + k0 + ac * 4);
      uint2 d;
      d.x = (u32)f2bf(v.x) | ((u32)f2bf(v.y) << 16);
      d.y = (u32)f2bf(v.z) | ((u32)f2bf(v.w) << 16);
      const int cs = a_chunk ^ ((ar >> 1) & 3);
      *(uint2*)&lA[ar * 32 + cs * 8 + a_half * 4] = d;
    }
    __syncthreads();
    bf16x8 afr[4], bfr[4];
#pragma unroll
    for (int m = 0; m < 4; ++m) {
      const int row = wr * 64 + m * 16 + fr;
      const int cs = kc ^ ((row >> 1) & 3);
      afr[m] = *(const bf16x8*)&lA[row * 32 + cs * 8];
    }
#pragma unroll
    for (int n = 0; n < 4; ++n) {
      const int row = wc * 64 + n * 16 + fr;
      const int cs = kc ^ ((row >> 1) & 3);
      bfr[n] = *(const bf16x8*)&lB[row * 32 + cs * 8];
    }
#pragma unroll
    for (int m = 0; m < 4; ++m)
#pragma unroll
      for (int n = 0; n < 4; ++n)
        acc[m][n] = __builtin_amdgcn_mfma_f32_16x16x32_bf16(afr[m], bfr[n],
                                                            acc[m][n], 0, 0, 0);
    __syncthreads();
  }
  const int ocol = lane & 15;
  const int orow = (lane >> 4) * 4;
#pragma unroll
  for (int m = 0; m < 4; ++m) {
    const size_t rbase = (r0 + wr * 64 + m * 16 + orow) * 1024;
#pragma unroll
    for (int n = 0; n < 4; ++n) {
      float* o = out + rbase + (c0 + wc * 64 + n * 16 + ocol);
      o[0] = acc[m][n][0];
      o[1024] = acc[m][n][1];
      o[2048] = acc[m][n][2];
      o[3072] = acc[m][n][3];
    }
  }
}

__global__ __launch_bounds__(256) void compute_M_fb(const float* __restrict__ W,
                                                    u16* __restrict__ Mb) {
  __shared__ float w1[32][64];
  __shared__ float w2[32][64];
  const int t = threadIdx.x;
  const int i0 = blockIdx.y * 64;
  const int j0 = blockIdx.x * 64;
  const int tx = t & 15, ty = t >> 4;
  float acc[4][4] = {};
  for (int u0 = 0; u0 < 1024; u0 += 32) {
    __syncthreads();
#pragma unroll
    for (int p = 0; p < 2; ++p) {
      int idx = p * 256 + t;
      int lu = idx >> 4, lc = (idx & 15) * 4;
      *(float4*)&w1[lu][lc] = *(const float4*)(W + (size_t)(u0 + lu) * 1024 + i0 + lc);
      *(float4*)&w2[lu][lc] = *(const float4*)(W + (size_t)(u0 + lu) * 1024 + j0 + lc);
    }
    __syncthreads();
#pragma unroll 8
    for (int u = 0; u < 32; ++u) {
      float4 a = *(const float4*)&w1[u][ty * 4];
      float4 b = *(const float4*)&w2[u][tx * 4];
      float av[4] = {a.x, a.y, a.z, a.w};
      float bv[4] = {b.x, b.y, b.z, b.w};
#pragma unroll
      for (int e = 0; e < 4; ++e)
#pragma unroll
        for (int f = 0; f < 4; ++f)
          acc[e][f] += av[e] * bv[f];
    }
  }
  const float s = 0.03125f;
#pragma unroll
  for (int e = 0; e < 4; ++e) {
    ushort4 v;
    v.x = f2bf(acc[e][0] * s);
    v.y = f2bf(acc[e][1] * s);
    v.z = f2bf(acc[e][2] * s);
    v.w = f2bf(acc[e][3] * s);
    *(ushort4*)(Mb + (size_t)(i0 + ty * 4 + e) * 1024 + j0 + tx * 4) = v;
  }
}

extern "C" void kernel_launch(void* const* d_in, const int* in_sizes, int n_in,
                              void* d_out, int out_size, void* d_ws, size_t ws_size,
                              hipStream_t stream) {
  const float* X = (const float*)d_in[0];
  const float* W = (const float*)d_in[1];
  float* out = (float*)d_out;
  u16* Mb = (u16*)d_ws;                                 // 2 MB
  u16* Xb = (u16*)((char*)d_ws + (size_t)(1 << 21));    // 128 MB

  const size_t need = (size_t)(1 << 21) + (size_t)64 * 1024 * 1024 * 2;
  if (ws_size >= need) {
    prep<<<2304, 256, 0, stream>>>(X, W, Xb, Mb);
    gemm_ad<<<1024, 512, 0, stream>>>(Xb, Mb, out);
  } else {
    compute_M_fb<<<dim3(16, 16), 256, 0, stream>>>(W, Mb);
    gemm_fused<<<4096, 256, 0, stream>>>(X, Mb, out);
  }
}